// Round 8
// baseline (110.145 us; speedup 1.0000x reference)
//
#include <hip/hip_runtime.h>
#include <math.h>

#define B_N 4096
#define M_N 256
#define D_N 256
#define ROWS 8                      // rows per k_gemm block
#define GRID_GEMM (B_N / ROWS)
#define GRID_RANK B_N
#define NSLOT 64                    // partial-sum slots (1 per 64B line)

constexpr float TAU_   = 0.2f;
constexpr float LAM_   = 8.0f;
constexpr float TOPO_  = 0.5f;
constexpr float LEN_C_ = 0.01f;
constexpr float SP_C_  = 0.001f;
constexpr float LOG2E_ = 1.44269504088896340736f;
constexpr float KSC    = LOG2E_ / TAU_;
constexpr float KL     = LOG2E_ / LAM_;
constexpr float C0_    = 133.0f;    // fixed exponent center: dist ~18.5 -> sc ~133

// ws float layout:
// [4]          cnt2 (uint, single)
// [16..272)    degree[256]
// [512..768)   wnorm[256]
// [1024..1280) pPart[256]
// [1280..1536) wpdPart[256]
// [2048..3072) S_slot[64] strided 16 floats (64B line each)
// [4096..5120) cnt1[64]  (uint) strided 16
// [8192..73728)      wT[256*256]  (D x M transpose)
// [131072..1179648)  distG[4096*256]  (~4 MB)

__device__ __forceinline__ float wave_reduce_sum(float v) {
#pragma unroll
  for (int off = 1; off < 64; off <<= 1) v += __shfl_xor(v, off, 64);
  return v;
}

// Dispatch 1: blocks 0..255 transpose w -> wT + wnorm + zero accumulators;
//             blocks 256..511 edge stats (direct proto-dist; self-contained,
//             no dependence on wT written by sibling blocks).
__global__ __launch_bounds__(256) void k_prep(const float* __restrict__ w,
                                              const float* __restrict__ E,
                                              float* __restrict__ ws) {
  int tid = threadIdx.x;
  if (blockIdx.x < M_N) {
    float* wT = ws + 8192;
    int j = blockIdx.x, d = tid;
    float v = w[j * D_N + d];
    wT[d * M_N + j] = v;
    float s = wave_reduce_sum(v * v);
    __shared__ float red[4];
    if ((d & 63) == 0) red[d >> 6] = s;
    if (j == 0) {
      if (d < 16) ws[d] = 0.0f;                       // cnt2 etc.
      if (d < NSLOT) {
        ws[2048 + 16 * d] = 0.0f;                     // S_slot
        ((unsigned*)ws)[4096 + 16 * d] = 0u;          // cnt1
      }
    }
    __syncthreads();
    if (d == 0) ws[512 + j] = red[0] + red[1] + red[2] + red[3];
  } else {
    int j = blockIdx.x - M_N;
    int k = tid;
    __shared__ __align__(16) float swj[D_N];
    __shared__ float redp[4], redw[4];
    swj[k] = w[j * D_N + k];
    __syncthreads();

    float l = 0.5f * (E[j * M_N + k] + E[k * M_N + j]);
    float p = __builtin_amdgcn_rcpf(1.0f + __builtin_amdgcn_exp2f(-l * LOG2E_));
    if (k == j) p = 0.0f;

    float pd = 0.0f;
    const float4* wr = (const float4*)(w + (size_t)k * D_N);
    const float4* sw = (const float4*)swj;
#pragma unroll 8
    for (int i = 0; i < D_N / 4; i++) {
      float4 a = wr[i], b = sw[i];
      float dx = a.x - b.x, dy = a.y - b.y, dz = a.z - b.z, dw = a.w - b.w;
      pd += dx * dx + dy * dy + dz * dz + dw * dw;
    }

    float sp  = wave_reduce_sum(p);
    float spd = wave_reduce_sum(p * pd);
    if ((k & 63) == 0) { redp[k >> 6] = sp; redw[k >> 6] = spd; }
    __syncthreads();
    if (k == 0) {
      float tp = redp[0] + redp[1] + redp[2] + redp[3];
      float tw = redw[0] + redw[1] + redw[2] + redw[3];
      ws[16 + j]   = tp * (1.0f / (float)(M_N - 1));
      ws[1024 + j] = tp;
      ws[1280 + j] = tw;
    }
  }
}

// Dispatch 2: GEMM -> distG. Thread owns column j; 8 rows per block halves
// wT L2 traffic vs ROWS=4 (same total FMA issue).
__global__ __launch_bounds__(256) void k_gemm(const float* __restrict__ data,
                                              float* __restrict__ ws) {
  const float* wT    = ws + 8192;
  const float* wnorm = ws + 512;
  float* distG = ws + 131072;

  __shared__ float rednrm[ROWS][4];
  __shared__ float snrm[ROWS];

  const int tid  = threadIdx.x;
  const int wv_  = tid >> 6;
  const int lane = tid & 63;
  const int b0   = blockIdx.x * ROWS;

  // row norms
#pragma unroll
  for (int r = 0; r < ROWS; r++) {
    float x = data[(size_t)(b0 + r) * D_N + tid];
    float s = wave_reduce_sum(x * x);
    if (lane == 0) rednrm[r][wv_] = s;
  }
  __syncthreads();
  if (tid < ROWS)
    snrm[tid] = rednrm[tid][0] + rednrm[tid][1] + rednrm[tid][2] + rednrm[tid][3];

  // x rows are block-uniform -> s_load float4; wT coalesced per thread
  const float4* xr[ROWS];
#pragma unroll
  for (int r = 0; r < ROWS; r++)
    xr[r] = (const float4*)(data + (size_t)(b0 + r) * D_N);

  float acc[ROWS];
#pragma unroll
  for (int r = 0; r < ROWS; r++) acc[r] = 0.0f;

#pragma unroll 2
  for (int d4 = 0; d4 < D_N / 4; d4++) {
    const float* p = wT + (size_t)(4 * d4) * M_N + tid;
    float w0 = p[0], w1 = p[M_N], w2 = p[2 * M_N], w3 = p[3 * M_N];
#pragma unroll
    for (int r = 0; r < ROWS; r++) {
      float4 xv = xr[r][d4];
      acc[r] = fmaf(xv.x, w0, acc[r]);
      acc[r] = fmaf(xv.y, w1, acc[r]);
      acc[r] = fmaf(xv.z, w2, acc[r]);
      acc[r] = fmaf(xv.w, w3, acc[r]);
    }
  }
  __syncthreads();   // snrm visible

  float wn = wnorm[tid];
#pragma unroll
  for (int r = 0; r < ROWS; r++) {
    float sq = snrm[r] - 2.0f * acc[r] + wn;
    distG[(size_t)(b0 + r) * M_N + tid] = sqrtf(fmaxf(sq, 0.0f));
  }
}

// Dispatch 3: rank. One row per block; j-independent (es,ep) pair terms
// precomputed once per row in LDS; hierarchical distributed atomics.
__global__ __launch_bounds__(256) void k_rank(float* __restrict__ ws,
                                              float* __restrict__ out) {
  const float* distG  = ws + 131072;
  const float* degree = ws + 16;
  float* S_slot  = ws + 2048;                 // stride 16 floats
  unsigned* cnt1 = (unsigned*)ws + 4096;      // stride 16
  unsigned* cnt2 = (unsigned*)ws + 4;

  __shared__ __align__(16) float ew[M_N];
  __shared__ __align__(16) float ewp[M_N];    // 128 pairs: [2p]=es, [2p+1]=ep
  __shared__ float redf[4], redp[4], redw[4];
  __shared__ int isLast;

  const int tid  = threadIdx.x;
  const int wv_  = tid >> 6;
  const int lane = tid & 63;
  const int row  = blockIdx.x;

  float dist = distG[(size_t)row * M_N + tid];
  float sc   = dist * KSC;
  float e    = __builtin_amdgcn_exp2f(sc - C0_);
  float iv   = __builtin_amdgcn_exp2f(C0_ - sc);
  float iv2  = iv * iv;
  ew[tid] = e;
  __syncthreads();
  if (tid < M_N / 2) {              // pair terms, shared by all j
    float ea = ew[2 * tid], eb = ew[2 * tid + 1];
    ewp[2 * tid]     = ea + eb;
    ewp[2 * tid + 1] = ea * eb;
  }
  __syncthreads();

  // sum_k sigmoid((d_j-d_k)/tau), pair-combined (1 rcp per 2 k)
  float s = 0.0f;
  const float4* q4 = (const float4*)ewp;
#pragma unroll 8
  for (int k4 = 0; k4 < M_N / 4; k4++) {
    float4 q = q4[k4];                         // (es_a, ep_a, es_b, ep_b)
    float t1 = iv * q.x;
    s = fmaf(t1 + 2.0f, __builtin_amdgcn_rcpf(fmaf(iv2, q.y, t1 + 1.0f)), s);
    float t2 = iv * q.z;
    s = fmaf(t2 + 2.0f, __builtin_amdgcn_rcpf(fmaf(iv2, q.w, t2 + 1.0f)), s);
  }

  // diagonal contributes exactly 0.5; soft_rank-1 = s-0.5
  float nb = __builtin_amdgcn_exp2f((0.5f - s) * KL);
  float tl = nb * dist * (1.0f + TOPO_ * degree[tid]);

  float bs = wave_reduce_sum(tl);
  if (lane == 0) redf[wv_] = bs;
  __syncthreads();
  if (tid == 0) {
    float tot = redf[0] + redf[1] + redf[2] + redf[3];
    int slot = row & (NSLOT - 1);
    float old = atomicAdd(&S_slot[16 * slot], tot);
    asm volatile("" : "+v"(old));   // consume: slot-add committed before cnt1
    int last = 0;
    unsigned t1 = atomicAdd(&cnt1[16 * slot], 1u);
    if (t1 == (unsigned)(B_N / NSLOT - 1)) {         // slot closed
      unsigned t2 = atomicAdd(cnt2, 1u);             // only 64 ever reach here
      last = (t2 == (unsigned)(NSLOT - 1)) ? 1 : 0;  // all slots closed
    }
    isLast = last;
  }
  __syncthreads();

  if (isLast) {
    float p  = ws[1024 + tid];
    float wd = ws[1280 + tid];
    float rp = wave_reduce_sum(p);
    float rw = wave_reduce_sum(wd);
    if (lane == 0) { redp[wv_] = rp; redw[wv_] = rw; }
    float sd = 0.0f;
    if (wv_ == 0) {
      float v = atomicAdd(&S_slot[16 * lane], 0.0f);  // coherent slot read
      sd = wave_reduce_sum(v);
    }
    __syncthreads();
    if (tid == 0) {
      float Sp   = redp[0] + redp[1] + redp[2] + redp[3];
      float Swpd = redw[0] + redw[1] + redw[2] + redw[3];
      float data_term = sd * (1.0f / ((float)B_N * (float)M_N));
      float wl = Swpd / (Sp + 1e-8f);
      float sparsity = Sp * (1.0f / ((float)M_N * (float)M_N));
      out[0] = data_term + LEN_C_ * wl + SP_C_ * sparsity;
    }
  }
}

extern "C" void kernel_launch(void* const* d_in, const int* in_sizes, int n_in,
                              void* d_out, int out_size, void* d_ws, size_t ws_size,
                              hipStream_t stream) {
  const float* data = (const float*)d_in[0];
  const float* w    = (const float*)d_in[1];
  const float* E    = (const float*)d_in[2];
  float* ws = (float*)d_ws;

  k_prep<<<2 * M_N, 256, 0, stream>>>(w, E, ws);
  k_gemm<<<GRID_GEMM, 256, 0, stream>>>(data, ws);
  k_rank<<<GRID_RANK, 256, 0, stream>>>(ws, (float*)d_out);
}

// Round 9
// 102.192 us; speedup vs baseline: 1.0778x; 1.0778x over previous
//
#include <hip/hip_runtime.h>
#include <math.h>

#define B_N 4096
#define M_N 256
#define D_N 256
#define ROWS 4                      // rows per k_main block
#define GRID_MAIN (B_N / ROWS)
#define NSLOT 64                    // partial-sum slots (1 per 64B line)
#define BLK_PER_SLOT (GRID_MAIN / NSLOT)

constexpr float TAU_   = 0.2f;
constexpr float LAM_   = 8.0f;
constexpr float TOPO_  = 0.5f;
constexpr float LEN_C_ = 0.01f;
constexpr float SP_C_  = 0.001f;
constexpr float LOG2E_ = 1.44269504088896340736f;
constexpr float KSC    = LOG2E_ / TAU_;
constexpr float KL     = LOG2E_ / LAM_;
constexpr float C0_    = 133.0f;    // fixed exponent center: dist ~18.5 -> sc ~133

// ws float layout:
// [4]          cnt2 (uint, single)
// [16..272)    degree[256]
// [512..768)   wnorm[256]
// [1024..1280) pPart[256]
// [1280..1536) wpdPart[256]
// [2048..3072) S_slot[64] strided 16 floats (64B line each)
// [4096..5120) cnt1[64]  (uint) strided 16
// [8192..73728) wT[256*256]  (D x M transpose)

__device__ __forceinline__ float wave_reduce_sum(float v) {
#pragma unroll
  for (int off = 1; off < 64; off <<= 1) v += __shfl_xor(v, off, 64);
  return v;
}

// Dispatch 1: blocks 0..255 transpose w -> wT + wnorm + zero accumulators;
//             blocks 256..511 edge stats (direct proto-dist; self-contained).
__global__ __launch_bounds__(256) void k_prep(const float* __restrict__ w,
                                              const float* __restrict__ E,
                                              float* __restrict__ ws) {
  int tid = threadIdx.x;
  if (blockIdx.x < M_N) {
    float* wT = ws + 8192;
    int j = blockIdx.x, d = tid;
    float v = w[j * D_N + d];
    wT[d * M_N + j] = v;
    float s = wave_reduce_sum(v * v);
    __shared__ float red[4];
    if ((d & 63) == 0) red[d >> 6] = s;
    if (j == 0) {
      if (d < 16) ws[d] = 0.0f;                       // cnt2 etc.
      if (d < NSLOT) {
        ws[2048 + 16 * d] = 0.0f;                     // S_slot
        ((unsigned*)ws)[4096 + 16 * d] = 0u;          // cnt1
      }
    }
    __syncthreads();
    if (d == 0) ws[512 + j] = red[0] + red[1] + red[2] + red[3];
  } else {
    int j = blockIdx.x - M_N;
    int k = tid;
    __shared__ __align__(16) float swj[D_N];
    __shared__ float redp[4], redw[4];
    swj[k] = w[j * D_N + k];
    __syncthreads();

    float l = 0.5f * (E[j * M_N + k] + E[k * M_N + j]);
    float p = __builtin_amdgcn_rcpf(1.0f + __builtin_amdgcn_exp2f(-l * LOG2E_));
    if (k == j) p = 0.0f;

    float pd = 0.0f;
    const float4* wr = (const float4*)(w + (size_t)k * D_N);
    const float4* sw = (const float4*)swj;
#pragma unroll 8
    for (int i = 0; i < D_N / 4; i++) {
      float4 a = wr[i], b = sw[i];
      float dx = a.x - b.x, dy = a.y - b.y, dz = a.z - b.z, dw = a.w - b.w;
      pd += dx * dx + dy * dy + dz * dz + dw * dw;
    }

    float sp  = wave_reduce_sum(p);
    float spd = wave_reduce_sum(p * pd);
    if ((k & 63) == 0) { redp[k >> 6] = sp; redw[k >> 6] = spd; }
    __syncthreads();
    if (k == 0) {
      float tp = redp[0] + redp[1] + redp[2] + redp[3];
      float tw = redw[0] + redw[1] + redw[2] + redw[3];
      ws[16 + j]   = tp * (1.0f / (float)(M_N - 1));
      ws[1024 + j] = tp;
      ws[1280 + j] = tw;
    }
  }
}

// Dispatch 2: fused GEMM + soft-rank. Thread owns column j=tid for 4 rows;
// dist stays in registers; rank uses hoisted per-row (es,ep) pair terms;
// hierarchical distributed atomics (16 blocks/slot); last block finalizes.
__global__ __launch_bounds__(256) void k_main(const float* __restrict__ data,
                                              float* __restrict__ ws,
                                              float* __restrict__ out) {
  const float* wT     = ws + 8192;
  const float* wnorm  = ws + 512;
  const float* degree = ws + 16;
  float* S_slot  = ws + 2048;                 // stride 16 floats
  unsigned* cnt1 = (unsigned*)ws + 4096;      // stride 16
  unsigned* cnt2 = (unsigned*)ws + 4;

  __shared__ __align__(16) float ew[ROWS][M_N];   // e-values per row
  __shared__ __align__(16) float ewp[ROWS][M_N];  // pairs: [2p]=es, [2p+1]=ep
  __shared__ float rednrm[ROWS][4];
  __shared__ float snrm[ROWS];
  __shared__ float redf[4], redp[4], redw[4];
  __shared__ int isLast;

  const int tid  = threadIdx.x;
  const int wv_  = tid >> 6;
  const int lane = tid & 63;
  const int b0   = blockIdx.x * ROWS;

  // row norms
#pragma unroll
  for (int r = 0; r < ROWS; r++) {
    float x = data[(size_t)(b0 + r) * D_N + tid];
    float s = wave_reduce_sum(x * x);
    if (lane == 0) rednrm[r][wv_] = s;
  }
  __syncthreads();
  if (tid < ROWS)
    snrm[tid] = rednrm[tid][0] + rednrm[tid][1] + rednrm[tid][2] + rednrm[tid][3];

  // GEMM: x rows block-uniform (s_load float4); wT coalesced per thread
  const float4* x0 = (const float4*)(data + (size_t)(b0 + 0) * D_N);
  const float4* x1 = (const float4*)(data + (size_t)(b0 + 1) * D_N);
  const float4* x2 = (const float4*)(data + (size_t)(b0 + 2) * D_N);
  const float4* x3 = (const float4*)(data + (size_t)(b0 + 3) * D_N);
  float a0 = 0.f, a1 = 0.f, a2 = 0.f, a3 = 0.f;
#pragma unroll 4
  for (int d4 = 0; d4 < D_N / 4; d4++) {
    float4 xa = x0[d4], xb = x1[d4], xc = x2[d4], xd = x3[d4];
    const float* p = wT + (size_t)(4 * d4) * M_N + tid;
    float w0 = p[0], w1 = p[M_N], w2 = p[2 * M_N], w3 = p[3 * M_N];
    a0 = fmaf(xa.x, w0, a0); a0 = fmaf(xa.y, w1, a0);
    a0 = fmaf(xa.z, w2, a0); a0 = fmaf(xa.w, w3, a0);
    a1 = fmaf(xb.x, w0, a1); a1 = fmaf(xb.y, w1, a1);
    a1 = fmaf(xb.z, w2, a1); a1 = fmaf(xb.w, w3, a1);
    a2 = fmaf(xc.x, w0, a2); a2 = fmaf(xc.y, w1, a2);
    a2 = fmaf(xc.z, w2, a2); a2 = fmaf(xc.w, w3, a2);
    a3 = fmaf(xd.x, w0, a3); a3 = fmaf(xd.y, w1, a3);
    a3 = fmaf(xd.z, w2, a3); a3 = fmaf(xd.w, w3, a3);
  }
  __syncthreads();   // snrm visible

  // distances + e-values (dist stays in registers for j = tid)
  float wn = wnorm[tid];
  float acc[ROWS] = {a0, a1, a2, a3};
  float dist[ROWS], iv[ROWS], iv2[ROWS];
#pragma unroll
  for (int r = 0; r < ROWS; r++) {
    float sq = snrm[r] - 2.0f * acc[r] + wn;
    dist[r] = sqrtf(fmaxf(sq, 0.0f));
    float sc = dist[r] * KSC;
    ew[r][tid] = __builtin_amdgcn_exp2f(sc - C0_);
    iv[r]      = __builtin_amdgcn_exp2f(C0_ - sc);
    iv2[r]     = iv[r] * iv[r];
  }
  __syncthreads();

  // hoisted pair terms: 4 rows x 128 pairs = 512 slots; thread does 2
#pragma unroll
  for (int h = 0; h < 2; h++) {
    int p  = tid + h * 256;
    int r  = p >> 7, idx = p & 127;
    float ea = ew[r][2 * idx], eb = ew[r][2 * idx + 1];
    ewp[r][2 * idx]     = ea + eb;
    ewp[r][2 * idx + 1] = ea * eb;
  }
  __syncthreads();

  // rank: per row, sum_k sigmoid((d_j-d_k)/tau), pair-combined
  float fj = 1.0f + TOPO_ * degree[tid];
  float tl = 0.0f;
#pragma unroll
  for (int r = 0; r < ROWS; r++) {
    float s = 0.0f;
    const float4* q4 = (const float4*)(&ewp[r][0]);
    float ivr = iv[r], iv2r = iv2[r];
#pragma unroll 8
    for (int k4 = 0; k4 < M_N / 4; k4++) {
      float4 q = q4[k4];                       // (es_a, ep_a, es_b, ep_b)
      float t1 = ivr * q.x;
      s = fmaf(t1 + 2.0f, __builtin_amdgcn_rcpf(fmaf(iv2r, q.y, t1 + 1.0f)), s);
      float t2 = ivr * q.z;
      s = fmaf(t2 + 2.0f, __builtin_amdgcn_rcpf(fmaf(iv2r, q.w, t2 + 1.0f)), s);
    }
    // diagonal contributes exactly 0.5; soft_rank-1 = s-0.5
    float nb = __builtin_amdgcn_exp2f((0.5f - s) * KL);
    tl = fmaf(nb * dist[r], fj, tl);
  }

  float bs = wave_reduce_sum(tl);
  if (lane == 0) redf[wv_] = bs;
  __syncthreads();
  if (tid == 0) {
    float tot = redf[0] + redf[1] + redf[2] + redf[3];
    int slot = (int)(blockIdx.x & (NSLOT - 1));
    float old = atomicAdd(&S_slot[16 * slot], tot);
    asm volatile("" : "+v"(old));   // consume: slot-add committed before cnt1
    int last = 0;
    unsigned t1 = atomicAdd(&cnt1[16 * slot], 1u);
    if (t1 == (unsigned)(BLK_PER_SLOT - 1)) {        // slot closed
      unsigned t2 = atomicAdd(cnt2, 1u);             // only 64 ever reach here
      last = (t2 == (unsigned)(NSLOT - 1)) ? 1 : 0;  // all slots closed
    }
    isLast = last;
  }
  __syncthreads();

  if (isLast) {
    float p  = ws[1024 + tid];
    float wd = ws[1280 + tid];
    float rp = wave_reduce_sum(p);
    float rw = wave_reduce_sum(wd);
    if (lane == 0) { redp[wv_] = rp; redw[wv_] = rw; }
    float sd = 0.0f;
    if (wv_ == 0) {
      float v = atomicAdd(&S_slot[16 * lane], 0.0f);  // coherent slot read
      sd = wave_reduce_sum(v);
    }
    __syncthreads();
    if (tid == 0) {
      float Sp   = redp[0] + redp[1] + redp[2] + redp[3];
      float Swpd = redw[0] + redw[1] + redw[2] + redw[3];
      float data_term = sd * (1.0f / ((float)B_N * (float)M_N));
      float wl = Swpd / (Sp + 1e-8f);
      float sparsity = Sp * (1.0f / ((float)M_N * (float)M_N));
      out[0] = data_term + LEN_C_ * wl + SP_C_ * sparsity;
    }
  }
}

extern "C" void kernel_launch(void* const* d_in, const int* in_sizes, int n_in,
                              void* d_out, int out_size, void* d_ws, size_t ws_size,
                              hipStream_t stream) {
  const float* data = (const float*)d_in[0];
  const float* w    = (const float*)d_in[1];
  const float* E    = (const float*)d_in[2];
  float* ws = (float*)d_ws;

  k_prep<<<2 * M_N, 256, 0, stream>>>(w, E, ws);
  k_main<<<GRID_MAIN, 256, 0, stream>>>(data, ws, (float*)d_out);
}